// Round 4
// baseline (83.930 us; speedup 1.0000x reference)
//
#include <hip/hip_runtime.h>

// VectorQuantizer: N=65536 rows, K=1024 codes, D=16, fp32.
// Out layout (fp32): z_q_st [0,1048576) | loss [1048576] | indices-as-float [1048577,1114113)
// R4: codebook via wave-uniform VECTOR global loads (L1/L2 broadcast, VMEM pipe,
//     deep pipelining) — zero LDS in the main loop. R=2 rows/lane, 512-thr blocks
//     (8 waves x K/8), NBLK=512 -> 2 blocks/CU = 4 waves/SIMD. Depth-1 e-prefetch.

constexpr int BLOCK = 512;
constexpr int NROWS = 65536;
constexpr int K = 1024;
constexpr int R = 2;                  // rows per lane
constexpr int RPB = 64 * R;           // 128 rows per block
constexpr int NBLK = NROWS / RPB;     // 512 blocks
constexpr int W = BLOCK / 64;         // 8 waves
constexpr int KPW = K / W;            // 128 codes per wave
constexpr int OFF_LOSS = 1048576;
constexpr int OFF_IDX  = 1048577;

// numpy pairwise_sum (n=16, unrolled-by-8 scalar path) of squares — bitwise-matches
// np.sum(x**2, axis=1): square (rounded, no fma), r[j]=s[j]+s[j+8], 3-level tree.
__device__ __forceinline__ float np_sumsq16(const float* a) {
  float s[16];
#pragma unroll
  for (int j = 0; j < 16; ++j) s[j] = __fmul_rn(a[j], a[j]);
  float r[8];
#pragma unroll
  for (int j = 0; j < 8; ++j) r[j] = __fadd_rn(s[j], s[j + 8]);
  const float t0 = __fadd_rn(r[0], r[1]);
  const float t1 = __fadd_rn(r[2], r[3]);
  const float t2 = __fadd_rn(r[4], r[5]);
  const float t3 = __fadd_rn(r[6], r[7]);
  return __fadd_rn(__fadd_rn(t0, t1), __fadd_rn(t2, t3));
}

// dist = R( R(z2 + e2k) - 2*dot ), dot = 4x4 fma tree (absmax 0 vs ref since R1 — keep).
__device__ __forceinline__ void dist_update(const float4 zr[4],
                                            const float4& e0, const float4& e1,
                                            const float4& e2, const float4& e3,
                                            float z2, float e2k, int k,
                                            float& best, int& bidx) {
  float c0 = zr[0].x * e0.x; c0 = fmaf(zr[0].y, e0.y, c0); c0 = fmaf(zr[0].z, e0.z, c0); c0 = fmaf(zr[0].w, e0.w, c0);
  float c1 = zr[1].x * e1.x; c1 = fmaf(zr[1].y, e1.y, c1); c1 = fmaf(zr[1].z, e1.z, c1); c1 = fmaf(zr[1].w, e1.w, c1);
  float c2 = zr[2].x * e2.x; c2 = fmaf(zr[2].y, e2.y, c2); c2 = fmaf(zr[2].z, e2.z, c2); c2 = fmaf(zr[2].w, e2.w, c2);
  float c3 = zr[3].x * e3.x; c3 = fmaf(zr[3].y, e3.y, c3); c3 = fmaf(zr[3].z, e3.z, c3); c3 = fmaf(zr[3].w, e3.w, c3);
  const float dot  = __fadd_rn(__fadd_rn(c0, c1), __fadd_rn(c2, c3));
  const float dist = __fmaf_rn(-2.0f, dot, __fadd_rn(z2, e2k));
  if (dist < best) { best = dist; bidx = k; }   // strict '<' keeps FIRST index (np.argmin)
}

__global__ __launch_bounds__(256)
void vq_pre(const float* __restrict__ emb, float* __restrict__ e2g) {
  const int k = blockIdx.x * 256 + threadIdx.x;   // 4 blocks x 256 = 1024
  const float4* g4 = reinterpret_cast<const float4*>(emb);
  float4 e[4];
#pragma unroll
  for (int i = 0; i < 4; ++i) e[i] = g4[k * 4 + i];
  e2g[k] = np_sumsq16(reinterpret_cast<const float*>(e));
}

__global__ __launch_bounds__(BLOCK, 4)   // cap VGPR<=128 -> 2 blocks/CU resident
void vq_main(const float* __restrict__ z, const float* __restrict__ emb,
             const float* __restrict__ e2g, float* __restrict__ out,
             float* __restrict__ partials) {
  __shared__ float sbest[W][RPB];    // 4 KB
  __shared__ int   sidx[W][RPB];     // 4 KB

  const int t = threadIdx.x;
  const int lane = t & 63;
  const int w = t >> 6;              // NOT readfirstlane'd: keep loads on the VECTOR pipe
  const int rowbase = blockIdx.x * RPB;

  // ---- my R z-rows + np-bitwise z2 ----
  const float4* z4 = reinterpret_cast<const float4*>(z);
  float4 zr[R][4];
  float  z2[R];
#pragma unroll
  for (int i = 0; i < R; ++i) {
    const int r = rowbase + i * 64 + lane;
#pragma unroll
    for (int j = 0; j < 4; ++j) zr[i][j] = z4[(size_t)r * 4 + j];
    z2[i] = np_sumsq16(reinterpret_cast<const float*>(zr[i]));
  }

  // ---- main loop over this wave's K/8 codes; e-rows via uniform global loads ----
  const int k0 = w * KPW;
  const float4* e4  = reinterpret_cast<const float4*>(emb) + (size_t)k0 * 4;
  const float*  e2p = e2g + k0;

  float best[R];
  int   bidx[R];
#pragma unroll
  for (int i = 0; i < R; ++i) { best[i] = __builtin_inff(); bidx[i] = 0; }

  float4 ec0 = e4[0], ec1 = e4[1], ec2 = e4[2], ec3 = e4[3];
  float  e2c = e2p[0];

#pragma unroll 2
  for (int kk = 0; kk < KPW - 1; ++kk) {
    // depth-1 prefetch of next code row (VMEM, hidden under compute below)
    const float4 en0 = e4[(kk + 1) * 4 + 0];
    const float4 en1 = e4[(kk + 1) * 4 + 1];
    const float4 en2 = e4[(kk + 1) * 4 + 2];
    const float4 en3 = e4[(kk + 1) * 4 + 3];
    const float  e2n = e2p[kk + 1];
    const int k = k0 + kk;
#pragma unroll
    for (int i = 0; i < R; ++i)
      dist_update(zr[i], ec0, ec1, ec2, ec3, z2[i], e2c, k, best[i], bidx[i]);
    ec0 = en0; ec1 = en1; ec2 = en2; ec3 = en3; e2c = e2n;
  }
#pragma unroll
  for (int i = 0; i < R; ++i)
    dist_update(zr[i], ec0, ec1, ec2, ec3, z2[i], e2c, k0 + KPW - 1, best[i], bidx[i]);

#pragma unroll
  for (int i = 0; i < R; ++i) {
    sbest[w][i * 64 + lane] = best[i];
    sidx[w][i * 64 + lane]  = bidx[i];
  }
  __syncthreads();

  // ---- wave 0 merges 8 k-slices for its own 2 rows (zr still in registers) ----
  if (t < 64) {
    float lsum = 0.f;
#pragma unroll
    for (int i = 0; i < R; ++i) {
      const int rl = i * 64 + lane;        // local row == the row zr[i] holds
      float b = sbest[0][rl]; int i0 = sidx[0][rl];
#pragma unroll
      for (int q = 1; q < W; ++q) {        // ascending k-slice order + '<' => first-index
        const float ob = sbest[q][rl]; const int oi = sidx[q][rl];
        if (ob < b) { b = ob; i0 = oi; }
      }
      // gather chosen code row (uniform-ish global, L1/L2 hit)
      const float4* eg = reinterpret_cast<const float4*>(emb);
      float4 e[4];
#pragma unroll
      for (int j = 0; j < 4; ++j) e[j] = eg[i0 * 4 + j];
      const float* zz = reinterpret_cast<const float*>(zr[i]);
      const float* ee = reinterpret_cast<const float*>(e);
      float4 ov[4];
      float* o = reinterpret_cast<float*>(ov);
#pragma unroll
      for (int j = 0; j < 16; ++j) {
        const float d = __fsub_rn(ee[j], zz[j]);   // z_q - z
        lsum = fmaf(d, d, lsum);                   // loss partial
        o[j] = __fadd_rn(zz[j], d);                // z + (z_q - z) == np z_q_st rounding
      }
      const int r = rowbase + rl;
      float4* o4 = reinterpret_cast<float4*>(out) + (size_t)r * 4;
#pragma unroll
      for (int j = 0; j < 4; ++j) o4[j] = ov[j];
      out[OFF_IDX + r] = (float)i0;
    }
    // deterministic wave reduction -> one partial per block
#pragma unroll
    for (int off = 32; off > 0; off >>= 1) lsum += __shfl_down(lsum, off);
    if (lane == 0) partials[blockIdx.x] = lsum;
  }
}

__global__ __launch_bounds__(256)
void vq_fin(const float* __restrict__ partials, float* __restrict__ out) {
  const int t = threadIdx.x;
  float v = partials[t] + partials[t + 256];     // 512 partials
#pragma unroll
  for (int off = 32; off > 0; off >>= 1) v += __shfl_down(v, off);
  __shared__ float s[4];
  if ((t & 63) == 0) s[t >> 6] = v;
  __syncthreads();
  if (t == 0) {
    const float S = (s[0] + s[1]) + (s[2] + s[3]);
    const float m = S / 1048576.0f;      // np.mean
    out[OFF_LOSS] = 1.25f * m;           // m + COMMITMENT_COST*m
  }
}

extern "C" void kernel_launch(void* const* d_in, const int* in_sizes, int n_in,
                              void* d_out, int out_size, void* d_ws, size_t ws_size,
                              hipStream_t stream) {
  const float* z   = reinterpret_cast<const float*>(d_in[0]);
  const float* emb = reinterpret_cast<const float*>(d_in[1]);
  float* out       = reinterpret_cast<float*>(d_out);
  float* e2g       = reinterpret_cast<float*>(d_ws);   // [0,1024) e2
  float* partials  = e2g + K;                          // [1024,1536) block partials
  vq_pre <<<K / 256, 256, 0, stream>>>(emb, e2g);
  vq_main<<<NBLK, BLOCK, 0, stream>>>(z, emb, e2g, out, partials);
  vq_fin <<<1, 256, 0, stream>>>(partials, out);
}

// Round 5
// 46.501 us; speedup vs baseline: 1.8049x; 1.8049x over previous
//
#include <hip/hip_runtime.h>

// VectorQuantizer: N=65536 rows, K=1024 codes, D=16, fp32.
// Out layout (fp32): z_q_st [0,1048576) | loss [1048576] | indices-as-float [1048577,1114113)
// R5: R1's LDS-broadcast codebook + occupancy fix: BLOCK=1024 (16 waves = 4/SIMD),
//     R=4 rows/lane, grid=256 = 1 block/CU, merge+epilogue fused in-kernel.

constexpr int BLOCK = 1024;
constexpr int NROWS = 65536;
constexpr int K = 1024;
constexpr int R = 4;                  // rows per lane
constexpr int RPB = 64 * R;           // 256 rows per block
constexpr int NBLK = NROWS / RPB;     // 256 blocks = 1 per CU
constexpr int W = BLOCK / 64;         // 16 waves
constexpr int KPW = K / W;            // 64 codes per wave
constexpr int OFF_LOSS = 1048576;
constexpr int OFF_IDX  = 1048577;

// numpy pairwise_sum (n=16, unrolled-by-8 scalar path) of squares — bitwise-matches
// np.sum(x**2, axis=1): square (rounded, no fma), r[j]=s[j]+s[j+8], 3-level tree.
__device__ __forceinline__ float np_sumsq16(const float* a) {
  float s[16];
#pragma unroll
  for (int j = 0; j < 16; ++j) s[j] = __fmul_rn(a[j], a[j]);
  float r[8];
#pragma unroll
  for (int j = 0; j < 8; ++j) r[j] = __fadd_rn(s[j], s[j + 8]);
  const float t0 = __fadd_rn(r[0], r[1]);
  const float t1 = __fadd_rn(r[2], r[3]);
  const float t2 = __fadd_rn(r[4], r[5]);
  const float t3 = __fadd_rn(r[6], r[7]);
  return __fadd_rn(__fadd_rn(t0, t1), __fadd_rn(t2, t3));
}

// dist = R( R(z2 + e2k) - 2*dot ), dot = 4x4 fma tree (absmax 0 vs ref since R1 — keep).
__device__ __forceinline__ void dist_update(const float4 zr[4],
                                            const float4& e0, const float4& e1,
                                            const float4& e2, const float4& e3,
                                            float z2, float e2k, int k,
                                            float& best, int& bidx) {
  float c0 = zr[0].x * e0.x; c0 = fmaf(zr[0].y, e0.y, c0); c0 = fmaf(zr[0].z, e0.z, c0); c0 = fmaf(zr[0].w, e0.w, c0);
  float c1 = zr[1].x * e1.x; c1 = fmaf(zr[1].y, e1.y, c1); c1 = fmaf(zr[1].z, e1.z, c1); c1 = fmaf(zr[1].w, e1.w, c1);
  float c2 = zr[2].x * e2.x; c2 = fmaf(zr[2].y, e2.y, c2); c2 = fmaf(zr[2].z, e2.z, c2); c2 = fmaf(zr[2].w, e2.w, c2);
  float c3 = zr[3].x * e3.x; c3 = fmaf(zr[3].y, e3.y, c3); c3 = fmaf(zr[3].z, e3.z, c3); c3 = fmaf(zr[3].w, e3.w, c3);
  const float dot  = __fadd_rn(__fadd_rn(c0, c1), __fadd_rn(c2, c3));
  const float dist = __fmaf_rn(-2.0f, dot, __fadd_rn(z2, e2k));
  if (dist < best) { best = dist; bidx = k; }   // strict '<' keeps FIRST index (np.argmin)
}

__global__ __launch_bounds__(BLOCK, 4)   // 16 waves = 4/EU -> VGPR cap 128, 1 block/CU
void vq_main(const float* __restrict__ z, const float* __restrict__ emb,
             float* __restrict__ out, float* __restrict__ partials) {
  __shared__ float4 se[K * 4];         // 64 KB codebook
  __shared__ float  se2[K];            // 4 KB ||e_k||^2
  __shared__ float  sbest[W][RPB];     // 16 KB
  __shared__ int    sidx[W][RPB];      // 16 KB
  __shared__ float  sred[4];

  const int t = threadIdx.x;
  const int lane = t & 63;
  const int w = t >> 6;                // 0..15
  const int rowbase = blockIdx.x * RPB;

  // ---- stage codebook (dense float4 copy, coalesced) ----
  const float4* g4 = reinterpret_cast<const float4*>(emb);
#pragma unroll
  for (int i = 0; i < 4; ++i) se[t + i * BLOCK] = g4[t + i * BLOCK];

  // ---- e2 inline from global re-reads (L1/L2 hits), np-bitwise; 1 code per thread ----
  {
    float4 e[4];
#pragma unroll
    for (int i = 0; i < 4; ++i) e[i] = g4[t * 4 + i];
    se2[t] = np_sumsq16(reinterpret_cast<const float*>(e));
  }

  // ---- my R z-rows + np-bitwise z2 (replicated per wave; L1-hit after first wave) ----
  const float4* z4 = reinterpret_cast<const float4*>(z);
  float4 zr[R][4];
  float  z2[R];
#pragma unroll
  for (int i = 0; i < R; ++i) {
    const int r = rowbase + i * 64 + lane;
#pragma unroll
    for (int j = 0; j < 4; ++j) zr[i][j] = z4[(size_t)r * 4 + j];
    z2[i] = np_sumsq16(reinterpret_cast<const float*>(zr[i]));
  }

  __syncthreads();

  // ---- main loop: this wave's K/16 codes; LDS reads wave-uniform (broadcast) ----
  float best[R];
  int   bidx[R];
#pragma unroll
  for (int i = 0; i < R; ++i) { best[i] = __builtin_inff(); bidx[i] = 0; }
  const int k0 = w * KPW;
#pragma unroll 2
  for (int kk = 0; kk < KPW; ++kk) {
    const int k = k0 + kk;
    const float4 e0 = se[k * 4 + 0];
    const float4 e1 = se[k * 4 + 1];
    const float4 e2 = se[k * 4 + 2];
    const float4 e3 = se[k * 4 + 3];
    const float  e2k = se2[k];
#pragma unroll
    for (int i = 0; i < R; ++i)
      dist_update(zr[i], e0, e1, e2, e3, z2[i], e2k, k, best[i], bidx[i]);
  }

#pragma unroll
  for (int i = 0; i < R; ++i) {
    sbest[w][i * 64 + lane] = best[i];
    sidx[w][i * 64 + lane]  = bidx[i];
  }
  __syncthreads();

  // ---- threads 0..255: merge 16 k-slices for row t, finalize ----
  if (t < RPB) {
    float b = sbest[0][t]; int i0 = sidx[0][t];
#pragma unroll
    for (int q = 1; q < W; ++q) {      // ascending k-slice order + strict '<' => first-index
      const float ob = sbest[q][t]; const int oi = sidx[q][t];
      if (ob < b || (ob == b && oi < i0)) { b = ob; i0 = oi; }
    }
    const int r = rowbase + t;
    float zz[16];
    float4* zzv = reinterpret_cast<float4*>(zz);
#pragma unroll
    for (int j = 0; j < 4; ++j) zzv[j] = z4[(size_t)r * 4 + j];   // L1/L2 re-read
    float4 e[4];
#pragma unroll
    for (int j = 0; j < 4; ++j) e[j] = se[i0 * 4 + j];            // LDS gather
    const float* ee = reinterpret_cast<const float*>(e);
    float4 ov[4];
    float* o = reinterpret_cast<float*>(ov);
    float lsum = 0.f;
#pragma unroll
    for (int j = 0; j < 16; ++j) {
      const float d = __fsub_rn(ee[j], zz[j]);   // z_q - z
      lsum = fmaf(d, d, lsum);                   // loss partial
      o[j] = __fadd_rn(zz[j], d);                // z + (z_q - z) == np z_q_st rounding
    }
    float4* o4 = reinterpret_cast<float4*>(out) + (size_t)r * 4;
#pragma unroll
    for (int j = 0; j < 4; ++j) o4[j] = ov[j];
    out[OFF_IDX + r] = (float)i0;

#pragma unroll
    for (int off = 32; off > 0; off >>= 1) lsum += __shfl_down(lsum, off);
    if (lane == 0) sred[w] = lsum;               // w in 0..3 here
  }
  __syncthreads();
  if (t == 0) partials[blockIdx.x] = (sred[0] + sred[1]) + (sred[2] + sred[3]);
}

__global__ __launch_bounds__(256)
void vq_fin(const float* __restrict__ partials, float* __restrict__ out) {
  const int t = threadIdx.x;
  float v = partials[t];                // 256 partials
#pragma unroll
  for (int off = 32; off > 0; off >>= 1) v += __shfl_down(v, off);
  __shared__ float s[4];
  if ((t & 63) == 0) s[t >> 6] = v;
  __syncthreads();
  if (t == 0) {
    const float S = (s[0] + s[1]) + (s[2] + s[3]);
    const float m = S / 1048576.0f;     // np.mean
    out[OFF_LOSS] = 1.25f * m;          // m + COMMITMENT_COST*m
  }
}

extern "C" void kernel_launch(void* const* d_in, const int* in_sizes, int n_in,
                              void* d_out, int out_size, void* d_ws, size_t ws_size,
                              hipStream_t stream) {
  const float* z   = reinterpret_cast<const float*>(d_in[0]);
  const float* emb = reinterpret_cast<const float*>(d_in[1]);
  float* out       = reinterpret_cast<float*>(d_out);
  float* partials  = reinterpret_cast<float*>(d_ws);   // 256 floats scratch
  vq_main<<<NBLK, BLOCK, 0, stream>>>(z, emb, out, partials);
  vq_fin <<<1, 256, 0, stream>>>(partials, out);
}